// Round 12
// baseline (199.055 us; speedup 1.0000x reference)
//
#include <hip/hip_runtime.h>
#include <math.h>

#define LATENT 1024
#define QDIM 256
#define NW 196608           // LATENT * CPG * K
#define BI 128
#define BC 32
#define TT 50
#define REGIONS 36
#define NGROUPS 16
#define CPG 64
#define NEG 0.1f

typedef __attribute__((ext_vector_type(8))) short short8;
typedef __attribute__((ext_vector_type(16))) float f32x16;

#define EL(v,c) ((c)==0?(v).x:(c)==1?(v).y:(c)==2?(v).z:(v).w)

__device__ __forceinline__ float leakyf(float x){ return x > 0.f ? x : NEG * x; }

__device__ __forceinline__ unsigned short f2bf(float x){
    union { float f; unsigned int u; } v; v.f = x;
    unsigned int r = v.u + 0x7FFFu + ((v.u >> 16) & 1u);   // RNE
    return (unsigned short)(r >> 16);
}

// ---------------------------------------------------------------------------
// Kernel 1a: masked mean + gate(pre-scaled by 1/36) + ||cap_repr||.
// ---------------------------------------------------------------------------
__global__ __launch_bounds__(256) void cap_mean_kernel(
    const float* __restrict__ cap_embed, const int* __restrict__ lens,
    float* __restrict__ cap_repr, float* __restrict__ cap_act,
    float* __restrict__ norm_capr)
{
    const int n = blockIdx.x;
    const int len = lens[n];
    const float invl = 1.f / (float)len;
    const int c4 = threadIdx.x;
    const float* base = cap_embed + (size_t)n * TT * LATENT + c4 * 4;
    float4 s = {0.f, 0.f, 0.f, 0.f};
    for (int t = 0; t < len; ++t) {
        const float4 v = *reinterpret_cast<const float4*>(base + (size_t)t * LATENT);
        s.x += v.x; s.y += v.y; s.z += v.z; s.w += v.w;
    }
    float4 m = {s.x * invl, s.y * invl, s.z * invl, s.w * invl};
    *reinterpret_cast<float4*>(cap_repr + n * LATENT + c4 * 4) = m;
    const float sc = 1.f / 36.f;
    float4 a = {leakyf(m.x) * sc, leakyf(m.y) * sc, leakyf(m.z) * sc, leakyf(m.w) * sc};
    *reinterpret_cast<float4*>(cap_act + n * LATENT + c4 * 4) = a;
    float ss = m.x*m.x + m.y*m.y + m.z*m.z + m.w*m.w;
    #pragma unroll
    for (int off = 32; off; off >>= 1) ss += __shfl_xor(ss, off);
    __shared__ float red4[4];
    if ((threadIdx.x & 63) == 0) red4[threadIdx.x >> 6] = ss;
    __syncthreads();
    if (threadIdx.x == 0) norm_capr[n] = sqrtf(red4[0] + red4[1] + red4[2] + red4[3]);
}

// ---------------------------------------------------------------------------
// Kernel 1b: q = cap_repr @ red_w + red_b, packed into bf16 frag layout
// qbfF: elem (r>>4)*512 + ((r>>3)&1)*256 + n*8 + (r&7)  (16KB total)
// ---------------------------------------------------------------------------
__global__ __launch_bounds__(256) void q_kernel(
    const float* __restrict__ cap_repr, const float* __restrict__ red_w,
    const float* __restrict__ red_b, unsigned short* __restrict__ qbfF)
{
    const int cg = blockIdx.x, n = blockIdx.y;
    const int col = threadIdx.x & 31, ks = threadIdx.x >> 5;
    const float* cr = cap_repr + n * LATENT;
    float p = 0.f;
    const int r0 = ks * 128;
    for (int r = r0; r < r0 + 128; ++r)
        p = fmaf(cr[r], red_w[(size_t)r * QDIM + cg * 32 + col], p);
    __shared__ float part[256];
    part[threadIdx.x] = p;
    __syncthreads();
    if (threadIdx.x < 32) {
        float s = red_b[cg * 32 + col];
        #pragma unroll
        for (int k = 0; k < 8; ++k) s += part[k * 32 + col];
        const int r = cg * 32 + col;
        const int elem = (r >> 4) * 512 + ((r >> 3) & 1) * 256 + n * 8 + (r & 7);
        qbfF[elem] = f2bf(s);
    }
}

// ---------------------------------------------------------------------------
// Kernel 2: wgen11 — MFMA W-GEMM with WIDE loads + LDS transpose.
// Block = 256 cols, 256 thr = 4 waves (wave owns 2 M-tiles of 32 cols).
// Per K-step (32 rows): dwordx4 loads (4 cols x f32, 1KB/wave-instr
// coalesced) -> f2bf pack -> LDS transpose [col][32r] stride-72B (2-way
// conflicts only) -> ds_read_b128 A-frags -> MFMA with q B-frags in regs.
// Logits+bias -> global f32 Lg[col][n] (coalesced). grid = 768 = 3/CU even.
// ---------------------------------------------------------------------------
__global__ __launch_bounds__(256) void wgen11_kernel(
    const unsigned short* __restrict__ qbfF, const float* __restrict__ proj_w,
    const float* __restrict__ proj_b, float* __restrict__ Lg)
{
    __shared__ unsigned short Bsm[256 * 36];   // [col][36] bf16 (pad 32->36), 18KB
    __shared__ float pbs[256];
    const int tid = threadIdx.x;
    const int colbase = blockIdx.x * 256;
    const int wv = tid >> 6, lane = tid & 63;
    const int lrow = lane & 31, khalf = lane >> 5;

    pbs[tid] = proj_b[colbase + tid];

    // B-frags: q in registers (16 x b128, coalesced, L2-hot)
    short8 qfr[16];
    {
        const unsigned short* qp = qbfF + (size_t)lane * 8;
        #pragma unroll
        for (int s = 0; s < 16; ++s) qfr[s] = *reinterpret_cast<const short8*>(qp + s * 512);
    }

    // staging role: cg = tid&63 (cols cg*4..+3), rq = tid>>6 (rows rq*8..+7)
    const int cg = tid & 63, rq = tid >> 6;
    const float* src0 = proj_w + (size_t)(rq * 8) * NW + colbase + cg * 4;

    float4 st[8], nx[8];
    #pragma unroll
    for (int j = 0; j < 8; ++j)
        st[j] = *reinterpret_cast<const float4*>(src0 + (size_t)j * NW);

    f32x16 acc0 = {}, acc1 = {};
    #pragma unroll
    for (int s = 0; s < 8; ++s) {              // K-step = 32 rows
        __syncthreads();                       // prev step's frag reads done
        #pragma unroll
        for (int cc = 0; cc < 4; ++cc) {       // transpose-pack: col -> 8 rows
            unsigned short pk[8];
            #pragma unroll
            for (int j = 0; j < 8; ++j) pk[j] = f2bf(EL(st[j], cc));
            *reinterpret_cast<short8*>((char*)Bsm + (cg * 4 + cc) * 72 + rq * 16) =
                *reinterpret_cast<const short8*>(pk);
        }
        __syncthreads();                       // tile visible
        if (s < 7) {                           // issue next step's wide loads
            const float* srcn = src0 + (size_t)((s + 1) * 32) * NW;
            #pragma unroll
            for (int j = 0; j < 8; ++j)
                nx[j] = *reinterpret_cast<const float4*>(srcn + (size_t)j * NW);
        }
        #pragma unroll
        for (int kc = 0; kc < 2; ++kc) {
            const short8 a0 = *reinterpret_cast<const short8*>(
                (char*)Bsm + (wv * 64 + lrow) * 72 + kc * 32 + khalf * 16);
            const short8 a1 = *reinterpret_cast<const short8*>(
                (char*)Bsm + (wv * 64 + 32 + lrow) * 72 + kc * 32 + khalf * 16);
            acc0 = __builtin_amdgcn_mfma_f32_32x32x16_bf16(a0, qfr[s * 2 + kc], acc0, 0, 0, 0);
            acc1 = __builtin_amdgcn_mfma_f32_32x32x16_bf16(a1, qfr[s * 2 + kc], acc1, 0, 0, 0);
        }
        if (s < 7) {
            #pragma unroll
            for (int j = 0; j < 8; ++j) st[j] = nx[j];
        }
    }

    // epilogue: Lg[col][n] = acc + bias (lanes n-consecutive -> 128B stores)
    // C/D: col(n)=lane&31, row(col_w)=(reg&3)+8*(reg>>2)+4*khalf
    #pragma unroll
    for (int reg = 0; reg < 16; ++reg) {
        const int rit = (reg & 3) + 8 * (reg >> 2) + 4 * khalf;
        const int c0 = wv * 64 + rit;
        const int c1 = c0 + 32;
        Lg[(size_t)(colbase + c0) * 32 + lrow] = acc0[reg] + pbs[c0];
        Lg[(size_t)(colbase + c1) * 32 + lrow] = acc1[reg] + pbs[c1];
    }
}

// ---------------------------------------------------------------------------
// Kernel 3: softmax2 — softmax(K=3) over Lg triples + frag-major bf16 pack.
// Block = 256 triples x 32 n; Lg reads 128B-coalesced. grid = 256.
// ---------------------------------------------------------------------------
__global__ __launch_bounds__(256) void softmax2_kernel(
    const float* __restrict__ Lg, unsigned short* __restrict__ Wp2F)
{
    const int tripbase = blockIdx.x * 256;
    for (int idx = threadIdx.x; idx < 8192; idx += 256) {
        const int n = idx & 31, it = idx >> 5;        // it < 256
        const int t = tripbase + it;                  // global triple = col/3
        const float x0 = Lg[(size_t)(t * 3 + 0) * 32 + n];
        const float x1 = Lg[(size_t)(t * 3 + 1) * 32 + n];
        const float x2 = Lg[(size_t)(t * 3 + 2) * 32 + n];
        const float m = fmaxf(fmaxf(x0, x1), x2);
        const float e0 = expf(x0 - m), e1 = expf(x1 - m), e2 = expf(x2 - m);
        const float inv = 1.f / (e0 + e1 + e2);
        const int g = t >> 12, o = (t >> 6) & 63, ii = t & 63;
        const int nt = o >> 5, lrow_o = o & 31;
        const int ks = ii >> 4, kh = (ii >> 3) & 1, j = ii & 7;
        const size_t base = (size_t)(n * 16 + g) * 12288
                          + (size_t)(nt * 4 + ks) * 512
                          + kh * 256 + lrow_o * 8 + j;
        Wp2F[base]        = f2bf(e0 * inv);   // k=0
        Wp2F[base + 4096] = f2bf(e1 * inv);   // k=1 (+8 frags)
        Wp2F[base + 8192] = f2bf(e2 * inv);   // k=2
    }
}

// ---------------------------------------------------------------------------
// Kernel 4: conv5 — 576 thr = 9 thin waves, 1 M-tile (32 rows) per wave.
// A-frags cached in registers; B double-buffered in LDS with reg-staged
// prefetch; 1 barrier/caption via Sw dbuf. grid = (g=16, bt=16, nq=2).
// ---------------------------------------------------------------------------
__global__ __launch_bounds__(576, 3) void conv5_kernel(
    const float* __restrict__ img_embed, const unsigned short* __restrict__ Wp2F,
    const float* __restrict__ cap_repr, const float* __restrict__ cap_act,
    float* __restrict__ part_dot, float* __restrict__ part_ss)
{
    const int g = blockIdx.x, bt = blockIdx.y, nq = blockIdx.z;
    const int b0 = bt * 8;
    __shared__ int4 BsmV[3072];            // 48KB: A-staging, then B dbuf 2x24KB
    char* BsmRaw = (char*)BsmV;
    __shared__ float Sw[2][9][2][64];      // double-buffered partials
    const int tid = threadIdx.x;
    const int wv = tid >> 6, lane = tid & 63;
    const int lrow = lane & 31, khalf = lane >> 5;
    const int ioff = khalf * 16;

    // ---- stage A (8 images, swizzled, fused f32->bf16) ----
    const float* imgG = img_embed + (size_t)b0 * 36 * 1024 + g * 64;
    for (int idx = tid; idx < 2304; idx += 576) {
        const int row_img = idx >> 3, ch = idx & 7;
        const int bbs = row_img / 36;
        const int l = row_img - bbs * 36;
        const float* src = imgG + (size_t)row_img * 1024 + ch * 8;
        const float4 u = *reinterpret_cast<const float4*>(src);
        const float4 v = *reinterpret_cast<const float4*>(src + 4);
        unsigned short r8[8];
        r8[0]=f2bf(u.x); r8[1]=f2bf(u.y); r8[2]=f2bf(u.z); r8[3]=f2bf(u.w);
        r8[4]=f2bf(v.x); r8[5]=f2bf(v.y); r8[6]=f2bf(v.z); r8[7]=f2bf(v.w);
        const int arow = bbs * 38 + l + 1;
        const int byte = (arow * 128 + ch * 16) ^ ((arow & 7) << 4);
        *reinterpret_cast<int4*>(BsmRaw + byte) = *reinterpret_cast<const int4*>(r8);
    }
    if (tid < 128) {   // zero pad rows (pos 0 and 37 per image)
        const int rr = tid >> 3, ch = tid & 7;
        const int arow = (rr >> 1) * 38 + (rr & 1) * 37;
        const int byte = (arow * 128 + ch * 16) ^ ((arow & 7) << 4);
        int4 z; z.x = 0; z.y = 0; z.z = 0; z.w = 0;
        *reinterpret_cast<int4*>(BsmRaw + byte) = z;
    }
    __syncthreads();

    // ---- A-frags to registers: wave wv owns rows [32wv, 32wv+32) ----
    const int rg = wv * 32 + lrow;
    const int bbr = rg / 36;
    const int abase = bbr * 38 + (rg - bbr * 36);
    short8 afr[3][4];
    #pragma unroll
    for (int k = 0; k < 3; ++k)
        #pragma unroll
        for (int ks = 0; ks < 4; ++ks) {
            const int arow = abase + k;
            const int byte = (arow * 128 + ks * 32 + ioff) ^ ((arow & 7) << 4);
            afr[k][ks] = *reinterpret_cast<const short8*>(BsmRaw + byte);
        }
    const int rbase = wv * 32;
    const int bfirst = rbase / 36;
    const int bsplit = (bfirst + 1) * 36 - rbase;   // tile-rows >= bsplit -> img bfirst+1
    __syncthreads();   // all A reads done; BsmRaw becomes B double-buffer

    // ---- B prologue: stage caption n0 into buf0 ----
    const int n0 = nq * 16;
    int4 st0, st1, st2;
    {
        const unsigned short* WF = Wp2F + (size_t)(n0 * 16 + g) * 12288;
        st0 = *reinterpret_cast<const int4*>(WF + (size_t)tid * 8);
        st1 = *reinterpret_cast<const int4*>(WF + (size_t)(tid + 576) * 8);
        if (tid < 384) st2 = *reinterpret_cast<const int4*>(WF + (size_t)(tid + 1152) * 8);
        *reinterpret_cast<int4*>(BsmRaw + (size_t)tid * 16) = st0;
        *reinterpret_cast<int4*>(BsmRaw + (size_t)(tid + 576) * 16) = st1;
        if (tid < 384) *reinterpret_cast<int4*>(BsmRaw + (size_t)(tid + 1152) * 16) = st2;
    }
    __syncthreads();

    for (int ni = 0; ni < 16; ++ni) {
        const int n = n0 + ni;
        char* Bcur = BsmRaw + (size_t)(ni & 1) * 24576;
        char* Bnxt = BsmRaw + (size_t)((ni + 1) & 1) * 24576;

        if (ni < 15) {   // issue next caption's loads (latency hidden by MFMA)
            const unsigned short* WF = Wp2F + (size_t)((n + 1) * 16 + g) * 12288;
            st0 = *reinterpret_cast<const int4*>(WF + (size_t)tid * 8);
            st1 = *reinterpret_cast<const int4*>(WF + (size_t)(tid + 576) * 8);
            if (tid < 384) st2 = *reinterpret_cast<const int4*>(WF + (size_t)(tid + 1152) * 8);
        }

        f32x16 acc0 = {}, acc1 = {};
        #pragma unroll
        for (int k = 0; k < 3; ++k) {
            #pragma unroll
            for (int ks = 0; ks < 4; ++ks) {
                const char* fb = Bcur + k * 8192 + ks * 1024 + (size_t)lane * 16;
                const short8 bf0 = *reinterpret_cast<const short8*>(fb);
                const short8 bf1 = *reinterpret_cast<const short8*>(fb + 4096);
                acc0 = __builtin_amdgcn_mfma_f32_32x32x16_bf16(afr[k][ks], bf0, acc0, 0, 0, 0);
                acc1 = __builtin_amdgcn_mfma_f32_32x32x16_bf16(afr[k][ks], bf1, acc1, 0, 0, 0);
            }
        }

        if (ni < 15) {   // write staged B into inactive buffer
            *reinterpret_cast<int4*>(Bnxt + (size_t)tid * 16) = st0;
            *reinterpret_cast<int4*>(Bnxt + (size_t)(tid + 576) * 16) = st1;
            if (tid < 384) *reinterpret_cast<int4*>(Bnxt + (size_t)(tid + 1152) * 16) = st2;
        }

        // epilogue: leaky + per-image column sums -> Sw[ni&1]
        float s0A = 0.f, s0B = 0.f, s1A = 0.f, s1B = 0.f;
        #pragma unroll
        for (int reg = 0; reg < 16; ++reg) {
            const int rit = (reg & 3) + 8 * (reg >> 2) + 4 * khalf;
            const float v0 = leakyf(acc0[reg]);
            const float v1 = leakyf(acc1[reg]);
            if (rit >= bsplit) { s0B += v0; s1B += v1; }
            else               { s0A += v0; s1A += v1; }
        }
        s0A += __shfl_xor(s0A, 32); s0B += __shfl_xor(s0B, 32);
        s1A += __shfl_xor(s1A, 32); s1B += __shfl_xor(s1B, 32);
        const int q = ni & 1;
        if (khalf == 0) {
            Sw[q][wv][0][lrow]      = s0A;
            Sw[q][wv][0][32 + lrow] = s1A;
            if (bsplit < 32) {
                Sw[q][wv][1][lrow]      = s0B;
                Sw[q][wv][1][32 + lrow] = s1B;
            }
        }
        __syncthreads();   // Sw[q] complete; Bnxt staged

        if (tid < 128) {   // gather: img b = waves {b,slot1}+{b+1,slot0} (b>0)
            const int b = tid >> 4, j = tid & 15;
            const float4 ca4 = *reinterpret_cast<const float4*>(&cap_act [n * LATENT + g * CPG + j * 4]);
            const float4 cr4 = *reinterpret_cast<const float4*>(&cap_repr[n * LATENT + g * CPG + j * 4]);
            const float cav[4] = {ca4.x, ca4.y, ca4.z, ca4.w};
            const float crv[4] = {cr4.x, cr4.y, cr4.z, cr4.w};
            float d = 0.f, ss = 0.f;
            #pragma unroll
            for (int u = 0; u < 4; ++u) {
                const int o = j * 4 + u;
                const float S = (b == 0)
                    ? Sw[q][0][0][o] + Sw[q][1][0][o]
                    : Sw[q][b][1][o] + Sw[q][b + 1][0][o];
                const float tmp = S * cav[u];          // cap_act pre-scaled by 1/36
                d = fmaf(tmp, crv[u], d);
                ss = fmaf(tmp, tmp, ss);
            }
            #pragma unroll
            for (int off = 1; off <= 8; off <<= 1) {
                d += __shfl_xor(d, off);
                ss += __shfl_xor(ss, off);
            }
            if (j == 0) {
                part_dot[((size_t)n * BI + b0 + b) * NGROUPS + g] = d;
                part_ss [((size_t)n * BI + b0 + b) * NGROUPS + g] = ss;
            }
        }
    }
}

// ---------------------------------------------------------------------------
// Kernel 5: combine 16 group-partials -> sims[b*32+n]
// ---------------------------------------------------------------------------
__global__ __launch_bounds__(256) void final_kernel(
    const float* __restrict__ part_dot, const float* __restrict__ part_ss,
    const float* __restrict__ norm_capr, float* __restrict__ out)
{
    const int idx = blockIdx.x * 256 + threadIdx.x;   // 4096
    const int n = idx & 31;
    const int b = idx >> 5;
    const size_t base = ((size_t)n * BI + b) * NGROUPS;
    float d = 0.f, s = 0.f;
    #pragma unroll
    for (int g = 0; g < NGROUPS; ++g) { d += part_dot[base + g]; s += part_ss[base + g]; }
    out[b * BC + n] = d / (sqrtf(s) * norm_capr[n]);
}

// ---------------------------------------------------------------------------
extern "C" void kernel_launch(void* const* d_in, const int* in_sizes, int n_in,
                              void* d_out, int out_size, void* d_ws, size_t ws_size,
                              hipStream_t stream) {
    const float* img_embed = (const float*)d_in[0];   // (128, 36, 1024)
    const float* cap_embed = (const float*)d_in[1];   // (32, 50, 1024)
    const int*   lens      = (const int*)  d_in[2];   // (32,)
    const float* red_w     = (const float*)d_in[3];   // (1024, 256)
    const float* red_b     = (const float*)d_in[4];   // (256,)
    const float* proj_w    = (const float*)d_in[5];   // (256, 196608)
    const float* proj_b    = (const float*)d_in[6];   // (196608,)
    float* out = (float*)d_out;                        // (128, 32)

    char* ws = (char*)d_ws;
    unsigned short* Wp2F = (unsigned short*)(ws);                      // 12,582,912 B
    float* Lg        = (float*)(ws + 12582912);                        // 25,165,824 B
    float* cap_repr  = (float*)(ws + 37748736);                        //    131,072 B
    float* cap_act   = (float*)(ws + 37879808);                        //    131,072 B
    unsigned short* qbfF = (unsigned short*)(ws + 38010880);           //     16,384 B
    float* norm_capr = (float*)(ws + 38027264);                        //        512 B
    float* part_dot  = (float*)(ws + 38027776);                        //    262,144 B
    float* part_ss   = (float*)(ws + 38289920);                        //    262,144 B

    hipLaunchKernelGGL(cap_mean_kernel, dim3(BC), dim3(256), 0, stream,
                       cap_embed, lens, cap_repr, cap_act, norm_capr);
    hipLaunchKernelGGL(q_kernel, dim3(8, BC), dim3(256), 0, stream,
                       cap_repr, red_w, red_b, qbfF);
    hipLaunchKernelGGL(wgen11_kernel, dim3(768), dim3(256), 0, stream,
                       qbfF, proj_w, proj_b, Lg);
    hipLaunchKernelGGL(softmax2_kernel, dim3(256), dim3(256), 0, stream,
                       Lg, Wp2F);
    hipLaunchKernelGGL(conv5_kernel, dim3(NGROUPS, 16, 2), dim3(576), 0, stream,
                       img_embed, Wp2F, cap_repr, cap_act, part_dot, part_ss);
    hipLaunchKernelGGL(final_kernel, dim3(16), dim3(256), 0, stream,
                       part_dot, part_ss, norm_capr, out);
}

// Round 13
// 179.392 us; speedup vs baseline: 1.1096x; 1.1096x over previous
//
#include <hip/hip_runtime.h>
#include <math.h>

#define LATENT 1024
#define QDIM 256
#define NW 196608           // LATENT * CPG * K
#define BI 128
#define BC 32
#define TT 50
#define REGIONS 36
#define NGROUPS 16
#define CPG 64
#define NEG 0.1f

typedef __attribute__((ext_vector_type(8))) short short8;
typedef __attribute__((ext_vector_type(16))) float f32x16;

__device__ __forceinline__ float leakyf(float x){ return x > 0.f ? x : NEG * x; }

__device__ __forceinline__ unsigned short f2bf(float x){
    union { float f; unsigned int u; } v; v.f = x;
    unsigned int r = v.u + 0x7FFFu + ((v.u >> 16) & 1u);   // RNE
    return (unsigned short)(r >> 16);
}

// ---------------------------------------------------------------------------
// Kernel 1a: masked mean + gate(pre-scaled by 1/36) + ||cap_repr||.
// ---------------------------------------------------------------------------
__global__ __launch_bounds__(256) void cap_mean_kernel(
    const float* __restrict__ cap_embed, const int* __restrict__ lens,
    float* __restrict__ cap_repr, float* __restrict__ cap_act,
    float* __restrict__ norm_capr)
{
    const int n = blockIdx.x;
    const int len = lens[n];
    const float invl = 1.f / (float)len;
    const int c4 = threadIdx.x;
    const float* base = cap_embed + (size_t)n * TT * LATENT + c4 * 4;
    float4 s = {0.f, 0.f, 0.f, 0.f};
    for (int t = 0; t < len; ++t) {
        const float4 v = *reinterpret_cast<const float4*>(base + (size_t)t * LATENT);
        s.x += v.x; s.y += v.y; s.z += v.z; s.w += v.w;
    }
    float4 m = {s.x * invl, s.y * invl, s.z * invl, s.w * invl};
    *reinterpret_cast<float4*>(cap_repr + n * LATENT + c4 * 4) = m;
    const float sc = 1.f / 36.f;
    float4 a = {leakyf(m.x) * sc, leakyf(m.y) * sc, leakyf(m.z) * sc, leakyf(m.w) * sc};
    *reinterpret_cast<float4*>(cap_act + n * LATENT + c4 * 4) = a;
    float ss = m.x*m.x + m.y*m.y + m.z*m.z + m.w*m.w;
    #pragma unroll
    for (int off = 32; off; off >>= 1) ss += __shfl_xor(ss, off);
    __shared__ float red4[4];
    if ((threadIdx.x & 63) == 0) red4[threadIdx.x >> 6] = ss;
    __syncthreads();
    if (threadIdx.x == 0) norm_capr[n] = sqrtf(red4[0] + red4[1] + red4[2] + red4[3]);
}

// ---------------------------------------------------------------------------
// Kernel 1b: q = cap_repr @ red_w + red_b, packed into bf16 frag layout
// qbfF: elem (r>>4)*512 + ((r>>3)&1)*256 + n*8 + (r&7)  (16KB total)
// ---------------------------------------------------------------------------
__global__ __launch_bounds__(256) void q_kernel(
    const float* __restrict__ cap_repr, const float* __restrict__ red_w,
    const float* __restrict__ red_b, unsigned short* __restrict__ qbfF)
{
    const int cg = blockIdx.x, n = blockIdx.y;
    const int col = threadIdx.x & 31, ks = threadIdx.x >> 5;
    const float* cr = cap_repr + n * LATENT;
    float p = 0.f;
    const int r0 = ks * 128;
    for (int r = r0; r < r0 + 128; ++r)
        p = fmaf(cr[r], red_w[(size_t)r * QDIM + cg * 32 + col], p);
    __shared__ float part[256];
    part[threadIdx.x] = p;
    __syncthreads();
    if (threadIdx.x < 32) {
        float s = red_b[cg * 32 + col];
        #pragma unroll
        for (int k = 0; k < 8; ++k) s += part[k * 32 + col];
        const int r = cg * 32 + col;
        const int elem = (r >> 4) * 512 + ((r >> 3) & 1) * 256 + n * 8 + (r & 7);
        qbfF[elem] = f2bf(s);
    }
}

// ---------------------------------------------------------------------------
// Kernel 2: wgen10 — wide-panel MFMA W-GEMM (round-10 best variant).
// Block = 768 cols, grid = 256 (1/CU). 512 thr = 8 waves; wave owns 3
// adjacent 32-col M-tiles. A = proj_w direct (f32->bf16 in reg); B = q frags.
// Logits -> 96KB f32 LDS; softmax(K=3) + frag-major pack epilogue.
// ---------------------------------------------------------------------------
__global__ __launch_bounds__(512, 2) void wgen10_kernel(
    const unsigned short* __restrict__ qbfF, const float* __restrict__ proj_w,
    const float* __restrict__ proj_b, unsigned short* __restrict__ Wp2F)
{
    __shared__ float L[768 * 32];      // 96KB logits [col][n]
    __shared__ float pbs[768];
    const int tid = threadIdx.x;
    const int bx = blockIdx.x;
    const int colbase = bx * 768;
    const int wv = tid >> 6, lane = tid & 63;
    const int lrow = lane & 31, khalf = lane >> 5;

    for (int i = tid; i < 768; i += 512) pbs[i] = proj_b[colbase + i];

    short8 qfr[16];
    {
        const unsigned short* qp = qbfF + (size_t)lane * 8;
        #pragma unroll
        for (int s = 0; s < 16; ++s)
            qfr[s] = *reinterpret_cast<const short8*>(qp + s * 512);
    }

    const float* pw0 = proj_w + (size_t)(khalf * 8) * NW + colbase + wv * 96 + lrow;
    const float* pw1 = pw0 + 32;
    const float* pw2 = pw0 + 64;

    float a0[8], a1[8], a2[8], b0[8], b1[8], b2[8];
    #pragma unroll
    for (int j = 0; j < 8; ++j) {
        a0[j] = pw0[(size_t)j * NW];
        a1[j] = pw1[(size_t)j * NW];
        a2[j] = pw2[(size_t)j * NW];
    }

    f32x16 acc0 = {}, acc1 = {}, acc2 = {};
    #pragma unroll
    for (int s = 0; s < 16; ++s) {
        if (s < 15) {
            const size_t roff = (size_t)((s + 1) * 16) * NW;
            #pragma unroll
            for (int j = 0; j < 8; ++j) {
                b0[j] = pw0[roff + (size_t)j * NW];
                b1[j] = pw1[roff + (size_t)j * NW];
                b2[j] = pw2[roff + (size_t)j * NW];
            }
        }
        unsigned short u0[8], u1[8], u2[8];
        #pragma unroll
        for (int j = 0; j < 8; ++j) {
            u0[j] = f2bf(a0[j]); u1[j] = f2bf(a1[j]); u2[j] = f2bf(a2[j]);
        }
        acc0 = __builtin_amdgcn_mfma_f32_32x32x16_bf16(*reinterpret_cast<const short8*>(u0), qfr[s], acc0, 0, 0, 0);
        acc1 = __builtin_amdgcn_mfma_f32_32x32x16_bf16(*reinterpret_cast<const short8*>(u1), qfr[s], acc1, 0, 0, 0);
        acc2 = __builtin_amdgcn_mfma_f32_32x32x16_bf16(*reinterpret_cast<const short8*>(u2), qfr[s], acc2, 0, 0, 0);
        #pragma unroll
        for (int j = 0; j < 8; ++j) { a0[j] = b0[j]; a1[j] = b1[j]; a2[j] = b2[j]; }
    }

    __syncthreads();
    #pragma unroll
    for (int reg = 0; reg < 16; ++reg) {
        const int rit = (reg & 3) + 8 * (reg >> 2) + 4 * khalf;
        const int c = wv * 96 + rit;
        L[c * 32 + lrow]        = acc0[reg] + pbs[c];
        L[(c + 32) * 32 + lrow] = acc1[reg] + pbs[c + 32];
        L[(c + 64) * 32 + lrow] = acc2[reg] + pbs[c + 64];
    }
    __syncthreads();

    const int g = bx >> 4;
    const int obase = (bx & 15) * 4;
    for (int idx = tid; idx < 8192; idx += 512) {
        const int n = idx & 31, i = idx >> 5;
        const int c = i * 3;
        const float x0 = L[c * 32 + n], x1 = L[(c+1)*32 + n], x2 = L[(c+2)*32 + n];
        const float m = fmaxf(fmaxf(x0, x1), x2);
        const float e0 = expf(x0 - m), e1 = expf(x1 - m), e2 = expf(x2 - m);
        const float inv = 1.f / (e0 + e1 + e2);
        const int o = obase + (i >> 6);
        const int ii = i & 63;
        const int nt = o >> 5, lrow_o = o & 31;
        const int ks = ii >> 4, kh = (ii >> 3) & 1, j = ii & 7;
        const size_t base = (size_t)(n * 16 + g) * 12288
                          + (size_t)(nt * 4 + ks) * 512
                          + kh * 256 + lrow_o * 8 + j;
        Wp2F[base]        = f2bf(e0 * inv);
        Wp2F[base + 4096] = f2bf(e1 * inv);
        Wp2F[base + 8192] = f2bf(e2 * inv);
    }
}

// ---------------------------------------------------------------------------
// Kernel 3: conv6 — 2 M-tiles per wave so each B-frag LDS read feeds 2 MFMAs
// (conv5 was LDS-issue bound at 1:1). 576 thr = 9 waves x 64 rows over a
// 16-image A-tile (76KB LDS, staged once). Low M-tile A-frags in registers,
// high M-tile A-frags from LDS. B double-buffered (reg-staged prefetch).
// grid = (g=16, bt=8, nq=2) = 256 blocks = exactly 1/CU, zero tail.
// ---------------------------------------------------------------------------
__global__ __launch_bounds__(576, 3) void conv6_kernel(
    const float* __restrict__ img_embed, const unsigned short* __restrict__ Wp2F,
    const float* __restrict__ cap_repr, const float* __restrict__ cap_act,
    float* __restrict__ part_dot, float* __restrict__ part_ss)
{
    const int g = blockIdx.x, bt = blockIdx.y, nq = blockIdx.z;
    const int b0 = bt * 16;                 // 16 images per block
    __shared__ char Asm[16 * 38 * 128];     // 77824 B, swizzled img tile
    __shared__ char Bd[2][24576];           // 49152 B, B double buffer
    __shared__ float Sw[2][18][2][64];      // 18432 B, per-32-row-tile partials
    const int tid = threadIdx.x;
    const int wv = tid >> 6, lane = tid & 63;
    const int lrow = lane & 31, khalf = lane >> 5;
    const int ioff = khalf * 16;

    // ---- stage A (16 images, swizzled, fused f32->bf16) ----
    const float* imgG = img_embed + (size_t)b0 * 36 * 1024 + g * 64;
    for (int idx = tid; idx < 4608; idx += 576) {
        const int row_img = idx >> 3, ch = idx & 7;
        const int bbs = row_img / 36;
        const int l = row_img - bbs * 36;
        const float* src = imgG + (size_t)row_img * 1024 + ch * 8;
        const float4 u = *reinterpret_cast<const float4*>(src);
        const float4 v = *reinterpret_cast<const float4*>(src + 4);
        unsigned short r8[8];
        r8[0]=f2bf(u.x); r8[1]=f2bf(u.y); r8[2]=f2bf(u.z); r8[3]=f2bf(u.w);
        r8[4]=f2bf(v.x); r8[5]=f2bf(v.y); r8[6]=f2bf(v.z); r8[7]=f2bf(v.w);
        const int arow = bbs * 38 + l + 1;
        const int byte = (arow * 128 + ch * 16) ^ ((arow & 7) << 4);
        *reinterpret_cast<int4*>(Asm + byte) = *reinterpret_cast<const int4*>(r8);
    }
    if (tid < 256) {   // zero pad rows (pos 0 and 37 per image): 32 rows x 8 ch
        const int rr = tid >> 3, ch = tid & 7;
        const int arow = (rr >> 1) * 38 + (rr & 1) * 37;
        const int byte = (arow * 128 + ch * 16) ^ ((arow & 7) << 4);
        int4 z; z.x = 0; z.y = 0; z.z = 0; z.w = 0;
        *reinterpret_cast<int4*>(Asm + byte) = z;
    }
    __syncthreads();

    // ---- low M-tile A-frags to registers: rows [wv*64, wv*64+32) ----
    const int rlo = wv * 64 + lrow;
    const int blo = rlo / 36;
    const int abase_lo = blo * 38 + (rlo - blo * 36);
    short8 afr[12];
    #pragma unroll
    for (int k = 0; k < 3; ++k)
        #pragma unroll
        for (int ks = 0; ks < 4; ++ks) {
            const int arow = abase_lo + k;
            const int byte = (arow * 128 + ks * 32 + ioff) ^ ((arow & 7) << 4);
            afr[k * 4 + ks] = *reinterpret_cast<const short8*>(Asm + byte);
        }
    // high M-tile A base: rows [wv*64+32, wv*64+64) — read from LDS per caption
    const int rhi = wv * 64 + 32 + lrow;
    const int bhi = rhi / 36;
    const int abase_hi = bhi * 38 + (rhi - bhi * 36);

    // tile bookkeeping (tiles of 32 rows; wave owns tiles 2wv, 2wv+1)
    int bfirstT[2], bsplitT[2];
    #pragma unroll
    for (int mt = 0; mt < 2; ++mt) {
        const int rbase = (2 * wv + mt) * 32;
        bfirstT[mt] = rbase / 36;
        bsplitT[mt] = (bfirstT[mt] + 1) * 36 - rbase;
    }

    // ---- B prologue: stage caption n0 into Bd[0] ----
    const int n0 = nq * 16;
    int4 st0, st1, st2;
    {
        const unsigned short* WF = Wp2F + (size_t)(n0 * 16 + g) * 12288;
        st0 = *reinterpret_cast<const int4*>(WF + (size_t)tid * 8);
        st1 = *reinterpret_cast<const int4*>(WF + (size_t)(tid + 576) * 8);
        if (tid < 384) st2 = *reinterpret_cast<const int4*>(WF + (size_t)(tid + 1152) * 8);
        *reinterpret_cast<int4*>(Bd[0] + (size_t)tid * 16) = st0;
        *reinterpret_cast<int4*>(Bd[0] + (size_t)(tid + 576) * 16) = st1;
        if (tid < 384) *reinterpret_cast<int4*>(Bd[0] + (size_t)(tid + 1152) * 16) = st2;
    }
    __syncthreads();

    for (int ni = 0; ni < 16; ++ni) {
        const int n = n0 + ni;
        char* Bcur = Bd[ni & 1];
        char* Bnxt = Bd[(ni + 1) & 1];

        if (ni < 15) {   // issue next caption's loads (hidden by MFMA phase)
            const unsigned short* WF = Wp2F + (size_t)((n + 1) * 16 + g) * 12288;
            st0 = *reinterpret_cast<const int4*>(WF + (size_t)tid * 8);
            st1 = *reinterpret_cast<const int4*>(WF + (size_t)(tid + 576) * 8);
            if (tid < 384) st2 = *reinterpret_cast<const int4*>(WF + (size_t)(tid + 1152) * 8);
        }

        f32x16 acc[2][2] = {};
        #pragma unroll
        for (int k = 0; k < 3; ++k) {
            #pragma unroll
            for (int ks = 0; ks < 4; ++ks) {
                const char* fb = Bcur + k * 8192 + ks * 1024 + (size_t)lane * 16;
                const short8 bf0 = *reinterpret_cast<const short8*>(fb);
                const short8 bf1 = *reinterpret_cast<const short8*>(fb + 4096);
                const int arh = abase_hi + k;
                const int byteH = (arh * 128 + ks * 32 + ioff) ^ ((arh & 7) << 4);
                const short8 ah = *reinterpret_cast<const short8*>(Asm + byteH);
                const short8 al = afr[k * 4 + ks];
                acc[0][0] = __builtin_amdgcn_mfma_f32_32x32x16_bf16(al, bf0, acc[0][0], 0, 0, 0);
                acc[0][1] = __builtin_amdgcn_mfma_f32_32x32x16_bf16(al, bf1, acc[0][1], 0, 0, 0);
                acc[1][0] = __builtin_amdgcn_mfma_f32_32x32x16_bf16(ah, bf0, acc[1][0], 0, 0, 0);
                acc[1][1] = __builtin_amdgcn_mfma_f32_32x32x16_bf16(ah, bf1, acc[1][1], 0, 0, 0);
            }
        }

        if (ni < 15) {   // write staged B into inactive buffer
            *reinterpret_cast<int4*>(Bnxt + (size_t)tid * 16) = st0;
            *reinterpret_cast<int4*>(Bnxt + (size_t)(tid + 576) * 16) = st1;
            if (tid < 384) *reinterpret_cast<int4*>(Bnxt + (size_t)(tid + 1152) * 16) = st2;
        }

        // epilogue: leaky + per-tile column sums -> Sw[ni&1]
        const int q = ni & 1;
        #pragma unroll
        for (int mt = 0; mt < 2; ++mt) {
            const int bsplit = bsplitT[mt];
            float s0A = 0.f, s0B = 0.f, s1A = 0.f, s1B = 0.f;
            #pragma unroll
            for (int reg = 0; reg < 16; ++reg) {
                const int rit = (reg & 3) + 8 * (reg >> 2) + 4 * khalf;
                const float v0 = leakyf(acc[mt][0][reg]);
                const float v1 = leakyf(acc[mt][1][reg]);
                if (rit >= bsplit) { s0B += v0; s1B += v1; }
                else               { s0A += v0; s1A += v1; }
            }
            s0A += __shfl_xor(s0A, 32); s0B += __shfl_xor(s0B, 32);
            s1A += __shfl_xor(s1A, 32); s1B += __shfl_xor(s1B, 32);
            if (khalf == 0) {
                const int t = 2 * wv + mt;
                Sw[q][t][0][lrow]      = s0A;
                Sw[q][t][0][32 + lrow] = s1A;
                if (bsplit < 32) {
                    Sw[q][t][1][lrow]      = s0B;
                    Sw[q][t][1][32 + lrow] = s1B;
                }
            }
        }
        __syncthreads();   // Sw[q] complete; Bnxt staged

        if (tid < 256) {   // gather: image b gets picks from tiles ta, ta+1
            const int b = tid >> 4, j = tid & 15;
            const int ta = (36 * b) >> 5;            // 36b/32
            const float4 ca4 = *reinterpret_cast<const float4*>(&cap_act [n * LATENT + g * CPG + j * 4]);
            const float4 cr4 = *reinterpret_cast<const float4*>(&cap_repr[n * LATENT + g * CPG + j * 4]);
            const float cav[4] = {ca4.x, ca4.y, ca4.z, ca4.w};
            const float crv[4] = {cr4.x, cr4.y, cr4.z, cr4.w};
            const int slotA = ((32 * ta) / 36 == b) ? 0 : 1;
            const int slotB = ((32 * (ta + 1)) / 36 == b) ? 0 : 1;
            float d = 0.f, ss = 0.f;
            #pragma unroll
            for (int u = 0; u < 4; ++u) {
                const int o = j * 4 + u;
                const float S = Sw[q][ta][slotA][o] + Sw[q][ta + 1][slotB][o];
                const float tmp = S * cav[u];          // cap_act pre-scaled by 1/36
                d = fmaf(tmp, crv[u], d);
                ss = fmaf(tmp, tmp, ss);
            }
            #pragma unroll
            for (int off = 1; off <= 8; off <<= 1) {
                d += __shfl_xor(d, off);
                ss += __shfl_xor(ss, off);
            }
            if (j == 0) {
                part_dot[((size_t)n * BI + b0 + b) * NGROUPS + g] = d;
                part_ss [((size_t)n * BI + b0 + b) * NGROUPS + g] = ss;
            }
        }
    }
}

// ---------------------------------------------------------------------------
// Kernel 4: combine 16 group-partials -> sims[b*32+n]
// ---------------------------------------------------------------------------
__global__ __launch_bounds__(256) void final_kernel(
    const float* __restrict__ part_dot, const float* __restrict__ part_ss,
    const float* __restrict__ norm_capr, float* __restrict__ out)
{
    const int idx = blockIdx.x * 256 + threadIdx.x;   // 4096
    const int n = idx & 31;
    const int b = idx >> 5;
    const size_t base = ((size_t)n * BI + b) * NGROUPS;
    float d = 0.f, s = 0.f;
    #pragma unroll
    for (int g = 0; g < NGROUPS; ++g) { d += part_dot[base + g]; s += part_ss[base + g]; }
    out[b * BC + n] = d / (sqrtf(s) * norm_capr[n]);
}

// ---------------------------------------------------------------------------
extern "C" void kernel_launch(void* const* d_in, const int* in_sizes, int n_in,
                              void* d_out, int out_size, void* d_ws, size_t ws_size,
                              hipStream_t stream) {
    const float* img_embed = (const float*)d_in[0];   // (128, 36, 1024)
    const float* cap_embed = (const float*)d_in[1];   // (32, 50, 1024)
    const int*   lens      = (const int*)  d_in[2];   // (32,)
    const float* red_w     = (const float*)d_in[3];   // (1024, 256)
    const float* red_b     = (const float*)d_in[4];   // (256,)
    const float* proj_w    = (const float*)d_in[5];   // (256, 196608)
    const float* proj_b    = (const float*)d_in[6];   // (196608,)
    float* out = (float*)d_out;                        // (128, 32)

    char* ws = (char*)d_ws;
    unsigned short* Wp2F   = (unsigned short*)(ws);                    // 12,582,912 B
    float* cap_repr  = (float*)(ws + 22020096);                        //    131,072 B
    float* cap_act   = (float*)(ws + 22151168);                        //    131,072 B
    unsigned short* qbfF = (unsigned short*)(ws + 22282240);           //     16,384 B
    float* norm_capr = (float*)(ws + 22315008);                        //        512 B
    float* part_dot  = (float*)(ws + 22315520);                        //    262,144 B
    float* part_ss   = (float*)(ws + 22577664);                        //    262,144 B

    hipLaunchKernelGGL(cap_mean_kernel, dim3(BC), dim3(256), 0, stream,
                       cap_embed, lens, cap_repr, cap_act, norm_capr);
    hipLaunchKernelGGL(q_kernel, dim3(8, BC), dim3(256), 0, stream,
                       cap_repr, red_w, red_b, qbfF);
    hipLaunchKernelGGL(wgen10_kernel, dim3(256), dim3(512), 0, stream,
                       qbfF, proj_w, proj_b, Wp2F);
    hipLaunchKernelGGL(conv6_kernel, dim3(NGROUPS, 8, 2), dim3(576), 0, stream,
                       img_embed, Wp2F, cap_repr, cap_act, part_dot, part_ss);
    hipLaunchKernelGGL(final_kernel, dim3(16), dim3(256), 0, stream,
                       part_dot, part_ss, norm_capr, out);
}

// Round 14
// 176.671 us; speedup vs baseline: 1.1267x; 1.0154x over previous
//
#include <hip/hip_runtime.h>
#include <math.h>

#define LATENT 1024
#define QDIM 256
#define NW 196608           // LATENT * CPG * K
#define BI 128
#define BC 32
#define TT 50
#define REGIONS 36
#define NGROUPS 16
#define CPG 64
#define NEG 0.1f

typedef __attribute__((ext_vector_type(8))) short short8;
typedef __attribute__((ext_vector_type(16))) float f32x16;

__device__ __forceinline__ float leakyf(float x){ return x > 0.f ? x : NEG * x; }

__device__ __forceinline__ unsigned short f2bf(float x){
    union { float f; unsigned int u; } v; v.f = x;
    unsigned int r = v.u + 0x7FFFu + ((v.u >> 16) & 1u);   // RNE
    return (unsigned short)(r >> 16);
}

// ---------------------------------------------------------------------------
// Kernel 1a: masked mean + gate(pre-scaled by 1/36) + ||cap_repr||.
// ---------------------------------------------------------------------------
__global__ __launch_bounds__(256) void cap_mean_kernel(
    const float* __restrict__ cap_embed, const int* __restrict__ lens,
    float* __restrict__ cap_repr, float* __restrict__ cap_act,
    float* __restrict__ norm_capr)
{
    const int n = blockIdx.x;
    const int len = lens[n];
    const float invl = 1.f / (float)len;
    const int c4 = threadIdx.x;
    const float* base = cap_embed + (size_t)n * TT * LATENT + c4 * 4;
    float4 s = {0.f, 0.f, 0.f, 0.f};
    for (int t = 0; t < len; ++t) {
        const float4 v = *reinterpret_cast<const float4*>(base + (size_t)t * LATENT);
        s.x += v.x; s.y += v.y; s.z += v.z; s.w += v.w;
    }
    float4 m = {s.x * invl, s.y * invl, s.z * invl, s.w * invl};
    *reinterpret_cast<float4*>(cap_repr + n * LATENT + c4 * 4) = m;
    const float sc = 1.f / 36.f;
    float4 a = {leakyf(m.x) * sc, leakyf(m.y) * sc, leakyf(m.z) * sc, leakyf(m.w) * sc};
    *reinterpret_cast<float4*>(cap_act + n * LATENT + c4 * 4) = a;
    float ss = m.x*m.x + m.y*m.y + m.z*m.z + m.w*m.w;
    #pragma unroll
    for (int off = 32; off; off >>= 1) ss += __shfl_xor(ss, off);
    __shared__ float red4[4];
    if ((threadIdx.x & 63) == 0) red4[threadIdx.x >> 6] = ss;
    __syncthreads();
    if (threadIdx.x == 0) norm_capr[n] = sqrtf(red4[0] + red4[1] + red4[2] + red4[3]);
}

// ---------------------------------------------------------------------------
// Kernel 1b: q = cap_repr @ red_w + red_b, packed into bf16 frag layout
// qbfF: elem (r>>4)*512 + ((r>>3)&1)*256 + n*8 + (r&7)  (16KB total)
// ---------------------------------------------------------------------------
__global__ __launch_bounds__(256) void q_kernel(
    const float* __restrict__ cap_repr, const float* __restrict__ red_w,
    const float* __restrict__ red_b, unsigned short* __restrict__ qbfF)
{
    const int cg = blockIdx.x, n = blockIdx.y;
    const int col = threadIdx.x & 31, ks = threadIdx.x >> 5;
    const float* cr = cap_repr + n * LATENT;
    float p = 0.f;
    const int r0 = ks * 128;
    for (int r = r0; r < r0 + 128; ++r)
        p = fmaf(cr[r], red_w[(size_t)r * QDIM + cg * 32 + col], p);
    __shared__ float part[256];
    part[threadIdx.x] = p;
    __syncthreads();
    if (threadIdx.x < 32) {
        float s = red_b[cg * 32 + col];
        #pragma unroll
        for (int k = 0; k < 8; ++k) s += part[k * 32 + col];
        const int r = cg * 32 + col;
        const int elem = (r >> 4) * 512 + ((r >> 3) & 1) * 256 + n * 8 + (r & 7);
        qbfF[elem] = f2bf(s);
    }
}

// ---------------------------------------------------------------------------
// Kernel 2: wgen10d — wgen10 with DEPTH-2 prefetch (48 outstanding f32
// loads/lane vs 24): tests whether the ~2 TB/s proj_w stream is
// outstanding-limited (Little's law) or externally capped.
// Block = 768 cols, grid = 256 (1/CU). 512 thr = 8 waves; wave owns 3
// adjacent 32-col M-tiles. A = proj_w direct (f32->bf16 in reg); B = q frags.
// Logits -> 96KB f32 LDS; softmax(K=3) + frag-major pack epilogue.
// ---------------------------------------------------------------------------
__global__ __launch_bounds__(512, 2) void wgen10d_kernel(
    const unsigned short* __restrict__ qbfF, const float* __restrict__ proj_w,
    const float* __restrict__ proj_b, unsigned short* __restrict__ Wp2F)
{
    __shared__ float L[768 * 32];      // 96KB logits [col][n]
    __shared__ float pbs[768];
    const int tid = threadIdx.x;
    const int bx = blockIdx.x;
    const int colbase = bx * 768;
    const int wv = tid >> 6, lane = tid & 63;
    const int lrow = lane & 31, khalf = lane >> 5;

    for (int i = tid; i < 768; i += 512) pbs[i] = proj_b[colbase + i];

    short8 qfr[16];
    {
        const unsigned short* qp = qbfF + (size_t)lane * 8;
        #pragma unroll
        for (int s = 0; s < 16; ++s)
            qfr[s] = *reinterpret_cast<const short8*>(qp + s * 512);
    }

    const float* pw0 = proj_w + (size_t)(khalf * 8) * NW + colbase + wv * 96 + lrow;
    const float* pw1 = pw0 + 32;
    const float* pw2 = pw0 + 64;

    // depth-2 prefetch buffers (even steps in A, odd steps in B)
    float bufA[24], bufB[24];
    #define ISSUE(BUF, S)                                                     \
        {                                                                     \
            const size_t roff = (size_t)((S) * 16) * NW;                      \
            _Pragma("unroll")                                                 \
            for (int j = 0; j < 8; ++j) {                                     \
                BUF[j]      = pw0[roff + (size_t)j * NW];                     \
                BUF[8 + j]  = pw1[roff + (size_t)j * NW];                     \
                BUF[16 + j] = pw2[roff + (size_t)j * NW];                     \
            }                                                                 \
        }
    #define CONSUME(BUF, S)                                                   \
        {                                                                     \
            unsigned short u0[8], u1[8], u2[8];                               \
            _Pragma("unroll")                                                 \
            for (int j = 0; j < 8; ++j) {                                     \
                u0[j] = f2bf(BUF[j]);                                         \
                u1[j] = f2bf(BUF[8 + j]);                                     \
                u2[j] = f2bf(BUF[16 + j]);                                    \
            }                                                                 \
            acc0 = __builtin_amdgcn_mfma_f32_32x32x16_bf16(                   \
                *reinterpret_cast<const short8*>(u0), qfr[S], acc0, 0, 0, 0); \
            acc1 = __builtin_amdgcn_mfma_f32_32x32x16_bf16(                   \
                *reinterpret_cast<const short8*>(u1), qfr[S], acc1, 0, 0, 0); \
            acc2 = __builtin_amdgcn_mfma_f32_32x32x16_bf16(                   \
                *reinterpret_cast<const short8*>(u2), qfr[S], acc2, 0, 0, 0); \
        }

    f32x16 acc0 = {}, acc1 = {}, acc2 = {};
    ISSUE(bufA, 0)
    ISSUE(bufB, 1)
    #pragma unroll
    for (int sp = 0; sp < 8; ++sp) {
        const int se = sp * 2, so = sp * 2 + 1;
        CONSUME(bufA, se)
        if (se + 2 < 16) ISSUE(bufA, se + 2)
        CONSUME(bufB, so)
        if (so + 2 < 16) ISSUE(bufB, so + 2)
    }
    #undef ISSUE
    #undef CONSUME

    __syncthreads();
    #pragma unroll
    for (int reg = 0; reg < 16; ++reg) {
        const int rit = (reg & 3) + 8 * (reg >> 2) + 4 * khalf;
        const int c = wv * 96 + rit;
        L[c * 32 + lrow]        = acc0[reg] + pbs[c];
        L[(c + 32) * 32 + lrow] = acc1[reg] + pbs[c + 32];
        L[(c + 64) * 32 + lrow] = acc2[reg] + pbs[c + 64];
    }
    __syncthreads();

    const int g = bx >> 4;
    const int obase = (bx & 15) * 4;
    for (int idx = tid; idx < 8192; idx += 512) {
        const int n = idx & 31, i = idx >> 5;
        const int c = i * 3;
        const float x0 = L[c * 32 + n], x1 = L[(c+1)*32 + n], x2 = L[(c+2)*32 + n];
        const float m = fmaxf(fmaxf(x0, x1), x2);
        const float e0 = expf(x0 - m), e1 = expf(x1 - m), e2 = expf(x2 - m);
        const float inv = 1.f / (e0 + e1 + e2);
        const int o = obase + (i >> 6);
        const int ii = i & 63;
        const int nt = o >> 5, lrow_o = o & 31;
        const int ks = ii >> 4, kh = (ii >> 3) & 1, j = ii & 7;
        const size_t base = (size_t)(n * 16 + g) * 12288
                          + (size_t)(nt * 4 + ks) * 512
                          + kh * 256 + lrow_o * 8 + j;
        Wp2F[base]        = f2bf(e0 * inv);
        Wp2F[base + 4096] = f2bf(e1 * inv);
        Wp2F[base + 8192] = f2bf(e2 * inv);
    }
}

// ---------------------------------------------------------------------------
// Kernel 3: conv5 — reverted to the measured-best conv (rounds 10/11).
// 576 thr = 9 thin waves, 1 M-tile (32 rows) per wave, A-frags in registers,
// B dbuf in LDS with reg-staged prefetch, 2 blocks/CU.
// grid = (g=16, bt=16, nq=2).
// ---------------------------------------------------------------------------
__global__ __launch_bounds__(576, 3) void conv5_kernel(
    const float* __restrict__ img_embed, const unsigned short* __restrict__ Wp2F,
    const float* __restrict__ cap_repr, const float* __restrict__ cap_act,
    float* __restrict__ part_dot, float* __restrict__ part_ss)
{
    const int g = blockIdx.x, bt = blockIdx.y, nq = blockIdx.z;
    const int b0 = bt * 8;
    __shared__ int4 BsmV[3072];            // 48KB: A-staging, then B dbuf 2x24KB
    char* BsmRaw = (char*)BsmV;
    __shared__ float Sw[2][9][2][64];      // double-buffered partials
    const int tid = threadIdx.x;
    const int wv = tid >> 6, lane = tid & 63;
    const int lrow = lane & 31, khalf = lane >> 5;
    const int ioff = khalf * 16;

    // ---- stage A (8 images, swizzled, fused f32->bf16) ----
    const float* imgG = img_embed + (size_t)b0 * 36 * 1024 + g * 64;
    for (int idx = tid; idx < 2304; idx += 576) {
        const int row_img = idx >> 3, ch = idx & 7;
        const int bbs = row_img / 36;
        const int l = row_img - bbs * 36;
        const float* src = imgG + (size_t)row_img * 1024 + ch * 8;
        const float4 u = *reinterpret_cast<const float4*>(src);
        const float4 v = *reinterpret_cast<const float4*>(src + 4);
        unsigned short r8[8];
        r8[0]=f2bf(u.x); r8[1]=f2bf(u.y); r8[2]=f2bf(u.z); r8[3]=f2bf(u.w);
        r8[4]=f2bf(v.x); r8[5]=f2bf(v.y); r8[6]=f2bf(v.z); r8[7]=f2bf(v.w);
        const int arow = bbs * 38 + l + 1;
        const int byte = (arow * 128 + ch * 16) ^ ((arow & 7) << 4);
        *reinterpret_cast<int4*>(BsmRaw + byte) = *reinterpret_cast<const int4*>(r8);
    }
    if (tid < 128) {   // zero pad rows (pos 0 and 37 per image)
        const int rr = tid >> 3, ch = tid & 7;
        const int arow = (rr >> 1) * 38 + (rr & 1) * 37;
        const int byte = (arow * 128 + ch * 16) ^ ((arow & 7) << 4);
        int4 z; z.x = 0; z.y = 0; z.z = 0; z.w = 0;
        *reinterpret_cast<int4*>(BsmRaw + byte) = z;
    }
    __syncthreads();

    // ---- A-frags to registers: wave wv owns rows [32wv, 32wv+32) ----
    const int rg = wv * 32 + lrow;
    const int bbr = rg / 36;
    const int abase = bbr * 38 + (rg - bbr * 36);
    short8 afr[3][4];
    #pragma unroll
    for (int k = 0; k < 3; ++k)
        #pragma unroll
        for (int ks = 0; ks < 4; ++ks) {
            const int arow = abase + k;
            const int byte = (arow * 128 + ks * 32 + ioff) ^ ((arow & 7) << 4);
            afr[k][ks] = *reinterpret_cast<const short8*>(BsmRaw + byte);
        }
    const int rbase = wv * 32;
    const int bfirst = rbase / 36;
    const int bsplit = (bfirst + 1) * 36 - rbase;   // tile-rows >= bsplit -> img bfirst+1
    __syncthreads();   // all A reads done; BsmRaw becomes B double-buffer

    // ---- B prologue: stage caption n0 into buf0 ----
    const int n0 = nq * 16;
    int4 st0, st1, st2;
    {
        const unsigned short* WF = Wp2F + (size_t)(n0 * 16 + g) * 12288;
        st0 = *reinterpret_cast<const int4*>(WF + (size_t)tid * 8);
        st1 = *reinterpret_cast<const int4*>(WF + (size_t)(tid + 576) * 8);
        if (tid < 384) st2 = *reinterpret_cast<const int4*>(WF + (size_t)(tid + 1152) * 8);
        *reinterpret_cast<int4*>(BsmRaw + (size_t)tid * 16) = st0;
        *reinterpret_cast<int4*>(BsmRaw + (size_t)(tid + 576) * 16) = st1;
        if (tid < 384) *reinterpret_cast<int4*>(BsmRaw + (size_t)(tid + 1152) * 16) = st2;
    }
    __syncthreads();

    for (int ni = 0; ni < 16; ++ni) {
        const int n = n0 + ni;
        char* Bcur = BsmRaw + (size_t)(ni & 1) * 24576;
        char* Bnxt = BsmRaw + (size_t)((ni + 1) & 1) * 24576;

        if (ni < 15) {   // issue next caption's loads (latency hidden by MFMA)
            const unsigned short* WF = Wp2F + (size_t)((n + 1) * 16 + g) * 12288;
            st0 = *reinterpret_cast<const int4*>(WF + (size_t)tid * 8);
            st1 = *reinterpret_cast<const int4*>(WF + (size_t)(tid + 576) * 8);
            if (tid < 384) st2 = *reinterpret_cast<const int4*>(WF + (size_t)(tid + 1152) * 8);
        }

        f32x16 acc0 = {}, acc1 = {};
        #pragma unroll
        for (int k = 0; k < 3; ++k) {
            #pragma unroll
            for (int ks = 0; ks < 4; ++ks) {
                const char* fb = Bcur + k * 8192 + ks * 1024 + (size_t)lane * 16;
                const short8 bf0 = *reinterpret_cast<const short8*>(fb);
                const short8 bf1 = *reinterpret_cast<const short8*>(fb + 4096);
                acc0 = __builtin_amdgcn_mfma_f32_32x32x16_bf16(afr[k][ks], bf0, acc0, 0, 0, 0);
                acc1 = __builtin_amdgcn_mfma_f32_32x32x16_bf16(afr[k][ks], bf1, acc1, 0, 0, 0);
            }
        }

        if (ni < 15) {   // write staged B into inactive buffer
            *reinterpret_cast<int4*>(Bnxt + (size_t)tid * 16) = st0;
            *reinterpret_cast<int4*>(Bnxt + (size_t)(tid + 576) * 16) = st1;
            if (tid < 384) *reinterpret_cast<int4*>(Bnxt + (size_t)(tid + 1152) * 16) = st2;
        }

        // epilogue: leaky + per-image column sums -> Sw[ni&1]
        float s0A = 0.f, s0B = 0.f, s1A = 0.f, s1B = 0.f;
        #pragma unroll
        for (int reg = 0; reg < 16; ++reg) {
            const int rit = (reg & 3) + 8 * (reg >> 2) + 4 * khalf;
            const float v0 = leakyf(acc0[reg]);
            const float v1 = leakyf(acc1[reg]);
            if (rit >= bsplit) { s0B += v0; s1B += v1; }
            else               { s0A += v0; s1A += v1; }
        }
        s0A += __shfl_xor(s0A, 32); s0B += __shfl_xor(s0B, 32);
        s1A += __shfl_xor(s1A, 32); s1B += __shfl_xor(s1B, 32);
        const int q = ni & 1;
        if (khalf == 0) {
            Sw[q][wv][0][lrow]      = s0A;
            Sw[q][wv][0][32 + lrow] = s1A;
            if (bsplit < 32) {
                Sw[q][wv][1][lrow]      = s0B;
                Sw[q][wv][1][32 + lrow] = s1B;
            }
        }
        __syncthreads();   // Sw[q] complete; Bnxt staged

        if (tid < 128) {   // gather: img b = waves {b,slot1}+{b+1,slot0} (b>0)
            const int b = tid >> 4, j = tid & 15;
            const float4 ca4 = *reinterpret_cast<const float4*>(&cap_act [n * LATENT + g * CPG + j * 4]);
            const float4 cr4 = *reinterpret_cast<const float4*>(&cap_repr[n * LATENT + g * CPG + j * 4]);
            const float cav[4] = {ca4.x, ca4.y, ca4.z, ca4.w};
            const float crv[4] = {cr4.x, cr4.y, cr4.z, cr4.w};
            float d = 0.f, ss = 0.f;
            #pragma unroll
            for (int u = 0; u < 4; ++u) {
                const int o = j * 4 + u;
                const float S = (b == 0)
                    ? Sw[q][0][0][o] + Sw[q][1][0][o]
                    : Sw[q][b][1][o] + Sw[q][b + 1][0][o];
                const float tmp = S * cav[u];          // cap_act pre-scaled by 1/36
                d = fmaf(tmp, crv[u], d);
                ss = fmaf(tmp, tmp, ss);
            }
            #pragma unroll
            for (int off = 1; off <= 8; off <<= 1) {
                d += __shfl_xor(d, off);
                ss += __shfl_xor(ss, off);
            }
            if (j == 0) {
                part_dot[((size_t)n * BI + b0 + b) * NGROUPS + g] = d;
                part_ss [((size_t)n * BI + b0 + b) * NGROUPS + g] = ss;
            }
        }
    }
}

// ---------------------------------------------------------------------------
// Kernel 4: combine 16 group-partials -> sims[b*32+n]
// ---------------------------------------------------------------------------
__global__ __launch_bounds__(256) void final_kernel(
    const float* __restrict__ part_dot, const float* __restrict__ part_ss,
    const float* __restrict__ norm_capr, float* __restrict__ out)
{
    const int idx = blockIdx.x * 256 + threadIdx.x;   // 4096
    const int n = idx & 31;
    const int b = idx >> 5;
    const size_t base = ((size_t)n * BI + b) * NGROUPS;
    float d = 0.f, s = 0.f;
    #pragma unroll
    for (int g = 0; g < NGROUPS; ++g) { d += part_dot[base + g]; s += part_ss[base + g]; }
    out[b * BC + n] = d / (sqrtf(s) * norm_capr[n]);
}

// ---------------------------------------------------------------------------
extern "C" void kernel_launch(void* const* d_in, const int* in_sizes, int n_in,
                              void* d_out, int out_size, void* d_ws, size_t ws_size,
                              hipStream_t stream) {
    const float* img_embed = (const float*)d_in[0];   // (128, 36, 1024)
    const float* cap_embed = (const float*)d_in[1];   // (32, 50, 1024)
    const int*   lens      = (const int*)  d_in[2];   // (32,)
    const float* red_w     = (const float*)d_in[3];   // (1024, 256)
    const float* red_b     = (const float*)d_in[4];   // (256,)
    const float* proj_w    = (const float*)d_in[5];   // (256, 196608)
    const float* proj_b    = (const float*)d_in[6];   // (196608,)
    float* out = (float*)d_out;                        // (128, 32)

    char* ws = (char*)d_ws;
    unsigned short* Wp2F   = (unsigned short*)(ws);                    // 12,582,912 B
    float* cap_repr  = (float*)(ws + 22020096);                        //    131,072 B
    float* cap_act   = (float*)(ws + 22151168);                        //    131,072 B
    unsigned short* qbfF = (unsigned short*)(ws + 22282240);           //     16,384 B
    float* norm_capr = (float*)(ws + 22315008);                        //        512 B
    float* part_dot  = (float*)(ws + 22315520);                        //    262,144 B
    float* part_ss   = (float*)(ws + 22577664);                        //    262,144 B

    hipLaunchKernelGGL(cap_mean_kernel, dim3(BC), dim3(256), 0, stream,
                       cap_embed, lens, cap_repr, cap_act, norm_capr);
    hipLaunchKernelGGL(q_kernel, dim3(8, BC), dim3(256), 0, stream,
                       cap_repr, red_w, red_b, qbfF);
    hipLaunchKernelGGL(wgen10d_kernel, dim3(256), dim3(512), 0, stream,
                       qbfF, proj_w, proj_b, Wp2F);
    hipLaunchKernelGGL(conv5_kernel, dim3(NGROUPS, 16, 2), dim3(576), 0, stream,
                       img_embed, Wp2F, cap_repr, cap_act, part_dot, part_ss);
    hipLaunchKernelGGL(final_kernel, dim3(16), dim3(256), 0, stream,
                       part_dot, part_ss, norm_capr, out);
}

// Round 15
// 174.551 us; speedup vs baseline: 1.1404x; 1.0122x over previous
//
#include <hip/hip_runtime.h>
#include <math.h>

#define LATENT 1024
#define QDIM 256
#define NW 196608           // LATENT * CPG * K
#define BI 128
#define BC 32
#define TT 50
#define REGIONS 36
#define NGROUPS 16
#define CPG 64
#define NEG 0.1f

typedef __attribute__((ext_vector_type(8))) short short8;
typedef __attribute__((ext_vector_type(16))) float f32x16;

__device__ __forceinline__ float leakyf(float x){ return x > 0.f ? x : NEG * x; }

__device__ __forceinline__ unsigned short f2bf(float x){
    union { float f; unsigned int u; } v; v.f = x;
    unsigned int r = v.u + 0x7FFFu + ((v.u >> 16) & 1u);   // RNE
    return (unsigned short)(r >> 16);
}

__device__ __forceinline__ unsigned long long pack4(float4 v){
    unsigned int lo = (unsigned int)f2bf(v.x) | ((unsigned int)f2bf(v.y) << 16);
    unsigned int hi = (unsigned int)f2bf(v.z) | ((unsigned int)f2bf(v.w) << 16);
    return (unsigned long long)lo | ((unsigned long long)hi << 32);
}

// ---------------------------------------------------------------------------
// Kernel 1a: masked mean + gate(pre-scaled by 1/36) + ||cap_repr||.
// ---------------------------------------------------------------------------
__global__ __launch_bounds__(256) void cap_mean_kernel(
    const float* __restrict__ cap_embed, const int* __restrict__ lens,
    float* __restrict__ cap_repr, float* __restrict__ cap_act,
    float* __restrict__ norm_capr)
{
    const int n = blockIdx.x;
    const int len = lens[n];
    const float invl = 1.f / (float)len;
    const int c4 = threadIdx.x;
    const float* base = cap_embed + (size_t)n * TT * LATENT + c4 * 4;
    float4 s = {0.f, 0.f, 0.f, 0.f};
    for (int t = 0; t < len; ++t) {
        const float4 v = *reinterpret_cast<const float4*>(base + (size_t)t * LATENT);
        s.x += v.x; s.y += v.y; s.z += v.z; s.w += v.w;
    }
    float4 m = {s.x * invl, s.y * invl, s.z * invl, s.w * invl};
    *reinterpret_cast<float4*>(cap_repr + n * LATENT + c4 * 4) = m;
    const float sc = 1.f / 36.f;
    float4 a = {leakyf(m.x) * sc, leakyf(m.y) * sc, leakyf(m.z) * sc, leakyf(m.w) * sc};
    *reinterpret_cast<float4*>(cap_act + n * LATENT + c4 * 4) = a;
    float ss = m.x*m.x + m.y*m.y + m.z*m.z + m.w*m.w;
    #pragma unroll
    for (int off = 32; off; off >>= 1) ss += __shfl_xor(ss, off);
    __shared__ float red4[4];
    if ((threadIdx.x & 63) == 0) red4[threadIdx.x >> 6] = ss;
    __syncthreads();
    if (threadIdx.x == 0) norm_capr[n] = sqrtf(red4[0] + red4[1] + red4[2] + red4[3]);
}

// ---------------------------------------------------------------------------
// Kernel 1b: q = cap_repr @ red_w + red_b, packed into bf16 frag layout
// qbfF: elem (r>>4)*512 + ((r>>3)&1)*256 + n*8 + (r&7)  (16KB total)
// ---------------------------------------------------------------------------
__global__ __launch_bounds__(256) void q_kernel(
    const float* __restrict__ cap_repr, const float* __restrict__ red_w,
    const float* __restrict__ red_b, unsigned short* __restrict__ qbfF)
{
    const int cg = blockIdx.x, n = blockIdx.y;
    const int col = threadIdx.x & 31, ks = threadIdx.x >> 5;
    const float* cr = cap_repr + n * LATENT;
    float p = 0.f;
    const int r0 = ks * 128;
    for (int r = r0; r < r0 + 128; ++r)
        p = fmaf(cr[r], red_w[(size_t)r * QDIM + cg * 32 + col], p);
    __shared__ float part[256];
    part[threadIdx.x] = p;
    __syncthreads();
    if (threadIdx.x < 32) {
        float s = red_b[cg * 32 + col];
        #pragma unroll
        for (int k = 0; k < 8; ++k) s += part[k * 32 + col];
        const int r = cg * 32 + col;
        const int elem = (r >> 4) * 512 + ((r >> 3) & 1) * 256 + n * 8 + (r & 7);
        qbfF[elem] = f2bf(s);
    }
}

// ---------------------------------------------------------------------------
// Kernel 2: wgen13 — wide-load + hardware-transpose-read W-GEMM.
// Tests the VMEM request-rate hypothesis cleanly: proj_w streamed with
// dwordx4 (1KB/wave-instr, dense) into per-WAVE LDS dbuf (no block
// barriers anywhere in the K-loop), MFMA A-frags delivered K-contiguous
// via ds_read_b64_tr_b16 (fixed 16-elem row stride; per-lane gather addr).
// Block = 768 cols, 768 thr = 12 waves (wave owns 64 cols = 2 M-tiles),
// grid = 256 (1/CU). B = q frags in registers. Fused softmax epilogue.
// LDS: staging 48KB + logits 96KB + bias 3KB = 147KB.
// ---------------------------------------------------------------------------
__global__ __launch_bounds__(768, 3) void wgen13_kernel(
    const unsigned short* __restrict__ qbfF, const float* __restrict__ proj_w,
    const float* __restrict__ proj_b, unsigned short* __restrict__ Wp2F)
{
    __shared__ unsigned short Stg[24576];   // 12 waves x 2 bufs x 1024 bf16
    __shared__ float L[768 * 32];           // logits [col][n]
    __shared__ float pbs[768];
    const int tid = threadIdx.x, bx = blockIdx.x;
    const int colbase = bx * 768;
    const int wv = tid >> 6, lane = tid & 63;
    const int lrow = lane & 31, khalf = lane >> 5;
    const int wcol = wv * 64;

    pbs[tid] = proj_b[colbase + tid];

    // B-frags: q in registers
    short8 qfr[16];
    {
        const unsigned short* qp = qbfF + (size_t)lane * 8;
        #pragma unroll
        for (int s = 0; s < 16; ++s) qfr[s] = *reinterpret_cast<const short8*>(qp + s * 512);
    }

    // staging role: lane covers cols 4*(lane&15).. +3 at rows rsub + 4i
    const int sc4 = lane & 15;
    const int rsub = lane >> 4;
    const float* gsrc = proj_w + colbase + wcol + sc4 * 4 + (size_t)rsub * NW;
    // LDS write element base within wave buffer (subtile [4r][16c] layout)
    const int ew = (sc4 >> 2) * 64 + rsub * 16 + (sc4 & 3) * 4;
    unsigned short* wbase = &Stg[wv * 2048];

    // tr-read byte addresses (per-lane gather: elem = col', stride 16 elems)
    const unsigned int stg0 = (unsigned int)(size_t)(void*)Stg + wv * 4096;
    const unsigned int et0 = ((khalf * 8 + 0 + (lrow >> 4)) * 64 + (lrow & 15)) * 2;
    const unsigned int et1 = ((khalf * 8 + 2 + (lrow >> 4)) * 64 + (lrow & 15)) * 2;

    // prologue: load step 0,1; pack step 0 -> buf0
    float4 gA[4], gB[4];
    #pragma unroll
    for (int i = 0; i < 4; ++i)
        gA[i] = *reinterpret_cast<const float4*>(gsrc + (size_t)(i * 4) * NW);
    #pragma unroll
    for (int i = 0; i < 4; ++i)
        gB[i] = *reinterpret_cast<const float4*>(gsrc + (size_t)(16 + i * 4) * NW);
    #pragma unroll
    for (int i = 0; i < 4; ++i)
        *reinterpret_cast<unsigned long long*>(&wbase[ew + i * 256]) = pack4(gA[i]);

    f32x16 acc0 = {}, acc1 = {};
    #pragma unroll
    for (int s = 0; s < 16; ++s) {
        // pack step s+1 into buf[(s+1)&1]; reload that register set with s+2
        if (s < 15) {
            if (((s + 1) & 1) == 1) {
                #pragma unroll
                for (int i = 0; i < 4; ++i)
                    *reinterpret_cast<unsigned long long*>(&wbase[1024 + ew + i * 256]) = pack4(gB[i]);
                if (s < 14) {
                    #pragma unroll
                    for (int i = 0; i < 4; ++i)
                        gB[i] = *reinterpret_cast<const float4*>(gsrc + (size_t)((s + 2) * 16 + i * 4) * NW);
                }
            } else {
                #pragma unroll
                for (int i = 0; i < 4; ++i)
                    *reinterpret_cast<unsigned long long*>(&wbase[ew + i * 256]) = pack4(gA[i]);
                if (s < 14) {
                    #pragma unroll
                    for (int i = 0; i < 4; ++i)
                        gA[i] = *reinterpret_cast<const float4*>(gsrc + (size_t)((s + 2) * 16 + i * 4) * NW);
                }
            }
        }

        // hardware transpose-reads of step s (buffer s&1), 2 M-tiles x 2 r-quads
        unsigned long long t00, t01, t10, t11;
        const unsigned int ab = stg0 + (unsigned int)((s & 1) * 2048);
        asm volatile("ds_read_b64_tr_b16 %0, %1" : "=v"(t00) : "v"(ab + et0) : "memory");
        asm volatile("ds_read_b64_tr_b16 %0, %1 offset:512" : "=v"(t01) : "v"(ab + et0) : "memory");
        asm volatile("ds_read_b64_tr_b16 %0, %1" : "=v"(t10) : "v"(ab + et1) : "memory");
        asm volatile("ds_read_b64_tr_b16 %0, %1 offset:512" : "=v"(t11) : "v"(ab + et1) : "memory");
        asm volatile("s_waitcnt lgkmcnt(0)" ::: "memory");
        __builtin_amdgcn_sched_barrier(0);
        union U { unsigned long long u[2]; short8 v; };
        U u0; u0.u[0] = t00; u0.u[1] = t01;
        U u1; u1.u[0] = t10; u1.u[1] = t11;
        acc0 = __builtin_amdgcn_mfma_f32_32x32x16_bf16(u0.v, qfr[s], acc0, 0, 0, 0);
        acc1 = __builtin_amdgcn_mfma_f32_32x32x16_bf16(u1.v, qfr[s], acc1, 0, 0, 0);
    }

    __syncthreads();   // pbs complete; staging dead
    // C: row(col_w) = (reg&3)+8*(reg>>2)+4*khalf, col(n) = lane&31
    #pragma unroll
    for (int reg = 0; reg < 16; ++reg) {
        const int rit = (reg & 3) + 8 * (reg >> 2) + 4 * khalf;
        const int c0 = wcol + rit, c1 = wcol + 32 + rit;
        L[c0 * 32 + lrow] = acc0[reg] + pbs[c0];
        L[c1 * 32 + lrow] = acc1[reg] + pbs[c1];
    }
    __syncthreads();

    // softmax over k-triples + frag-major bf16 pack (256 triples x 32 n)
    const int g = bx >> 4;
    const int obase = (bx & 15) * 4;
    for (int idx = tid; idx < 8192; idx += 768) {
        const int n = idx & 31, i = idx >> 5;
        const int c = i * 3;
        const float x0 = L[c * 32 + n], x1 = L[(c+1)*32 + n], x2 = L[(c+2)*32 + n];
        const float m = fmaxf(fmaxf(x0, x1), x2);
        const float e0 = expf(x0 - m), e1 = expf(x1 - m), e2 = expf(x2 - m);
        const float inv = 1.f / (e0 + e1 + e2);
        const int o = obase + (i >> 6);
        const int ii = i & 63;
        const int nt = o >> 5, lrow_o = o & 31;
        const int ks = ii >> 4, kh = (ii >> 3) & 1, j = ii & 7;
        const size_t base = (size_t)(n * 16 + g) * 12288
                          + (size_t)(nt * 4 + ks) * 512
                          + kh * 256 + lrow_o * 8 + j;
        Wp2F[base]        = f2bf(e0 * inv);
        Wp2F[base + 4096] = f2bf(e1 * inv);
        Wp2F[base + 8192] = f2bf(e2 * inv);
    }
}

// ---------------------------------------------------------------------------
// Kernel 3: conv5 — measured-best conv. 576 thr = 9 thin waves, 1 M-tile
// per wave, A-frags in registers, B dbuf in LDS with reg-staged prefetch.
// grid = (g=16, bt=16, nq=2).
// ---------------------------------------------------------------------------
__global__ __launch_bounds__(576, 3) void conv5_kernel(
    const float* __restrict__ img_embed, const unsigned short* __restrict__ Wp2F,
    const float* __restrict__ cap_repr, const float* __restrict__ cap_act,
    float* __restrict__ part_dot, float* __restrict__ part_ss)
{
    const int g = blockIdx.x, bt = blockIdx.y, nq = blockIdx.z;
    const int b0 = bt * 8;
    __shared__ int4 BsmV[3072];            // 48KB: A-staging, then B dbuf 2x24KB
    char* BsmRaw = (char*)BsmV;
    __shared__ float Sw[2][9][2][64];      // double-buffered partials
    const int tid = threadIdx.x;
    const int wv = tid >> 6, lane = tid & 63;
    const int lrow = lane & 31, khalf = lane >> 5;
    const int ioff = khalf * 16;

    // ---- stage A (8 images, swizzled, fused f32->bf16) ----
    const float* imgG = img_embed + (size_t)b0 * 36 * 1024 + g * 64;
    for (int idx = tid; idx < 2304; idx += 576) {
        const int row_img = idx >> 3, ch = idx & 7;
        const int bbs = row_img / 36;
        const int l = row_img - bbs * 36;
        const float* src = imgG + (size_t)row_img * 1024 + ch * 8;
        const float4 u = *reinterpret_cast<const float4*>(src);
        const float4 v = *reinterpret_cast<const float4*>(src + 4);
        unsigned short r8[8];
        r8[0]=f2bf(u.x); r8[1]=f2bf(u.y); r8[2]=f2bf(u.z); r8[3]=f2bf(u.w);
        r8[4]=f2bf(v.x); r8[5]=f2bf(v.y); r8[6]=f2bf(v.z); r8[7]=f2bf(v.w);
        const int arow = bbs * 38 + l + 1;
        const int byte = (arow * 128 + ch * 16) ^ ((arow & 7) << 4);
        *reinterpret_cast<int4*>(BsmRaw + byte) = *reinterpret_cast<const int4*>(r8);
    }
    if (tid < 128) {   // zero pad rows (pos 0 and 37 per image)
        const int rr = tid >> 3, ch = tid & 7;
        const int arow = (rr >> 1) * 38 + (rr & 1) * 37;
        const int byte = (arow * 128 + ch * 16) ^ ((arow & 7) << 4);
        int4 z; z.x = 0; z.y = 0; z.z = 0; z.w = 0;
        *reinterpret_cast<int4*>(BsmRaw + byte) = z;
    }
    __syncthreads();

    // ---- A-frags to registers: wave wv owns rows [32wv, 32wv+32) ----
    const int rg = wv * 32 + lrow;
    const int bbr = rg / 36;
    const int abase = bbr * 38 + (rg - bbr * 36);
    short8 afr[3][4];
    #pragma unroll
    for (int k = 0; k < 3; ++k)
        #pragma unroll
        for (int ks = 0; ks < 4; ++ks) {
            const int arow = abase + k;
            const int byte = (arow * 128 + ks * 32 + ioff) ^ ((arow & 7) << 4);
            afr[k][ks] = *reinterpret_cast<const short8*>(BsmRaw + byte);
        }
    const int rbase = wv * 32;
    const int bfirst = rbase / 36;
    const int bsplit = (bfirst + 1) * 36 - rbase;   // tile-rows >= bsplit -> img bfirst+1
    __syncthreads();   // all A reads done; BsmRaw becomes B double-buffer

    // ---- B prologue: stage caption n0 into buf0 ----
    const int n0 = nq * 16;
    int4 st0, st1, st2;
    {
        const unsigned short* WF = Wp2F + (size_t)(n0 * 16 + g) * 12288;
        st0 = *reinterpret_cast<const int4*>(WF + (size_t)tid * 8);
        st1 = *reinterpret_cast<const int4*>(WF + (size_t)(tid + 576) * 8);
        if (tid < 384) st2 = *reinterpret_cast<const int4*>(WF + (size_t)(tid + 1152) * 8);
        *reinterpret_cast<int4*>(BsmRaw + (size_t)tid * 16) = st0;
        *reinterpret_cast<int4*>(BsmRaw + (size_t)(tid + 576) * 16) = st1;
        if (tid < 384) *reinterpret_cast<int4*>(BsmRaw + (size_t)(tid + 1152) * 16) = st2;
    }
    __syncthreads();

    for (int ni = 0; ni < 16; ++ni) {
        const int n = n0 + ni;
        char* Bcur = BsmRaw + (size_t)(ni & 1) * 24576;
        char* Bnxt = BsmRaw + (size_t)((ni + 1) & 1) * 24576;

        if (ni < 15) {   // issue next caption's loads (latency hidden by MFMA)
            const unsigned short* WF = Wp2F + (size_t)((n + 1) * 16 + g) * 12288;
            st0 = *reinterpret_cast<const int4*>(WF + (size_t)tid * 8);
            st1 = *reinterpret_cast<const int4*>(WF + (size_t)(tid + 576) * 8);
            if (tid < 384) st2 = *reinterpret_cast<const int4*>(WF + (size_t)(tid + 1152) * 8);
        }

        f32x16 acc0 = {}, acc1 = {};
        #pragma unroll
        for (int k = 0; k < 3; ++k) {
            #pragma unroll
            for (int ks = 0; ks < 4; ++ks) {
                const char* fb = Bcur + k * 8192 + ks * 1024 + (size_t)lane * 16;
                const short8 bf0 = *reinterpret_cast<const short8*>(fb);
                const short8 bf1 = *reinterpret_cast<const short8*>(fb + 4096);
                acc0 = __builtin_amdgcn_mfma_f32_32x32x16_bf16(afr[k][ks], bf0, acc0, 0, 0, 0);
                acc1 = __builtin_amdgcn_mfma_f32_32x32x16_bf16(afr[k][ks], bf1, acc1, 0, 0, 0);
            }
        }

        if (ni < 15) {   // write staged B into inactive buffer
            *reinterpret_cast<int4*>(Bnxt + (size_t)tid * 16) = st0;
            *reinterpret_cast<int4*>(Bnxt + (size_t)(tid + 576) * 16) = st1;
            if (tid < 384) *reinterpret_cast<int4*>(Bnxt + (size_t)(tid + 1152) * 16) = st2;
        }

        // epilogue: leaky + per-image column sums -> Sw[ni&1]
        float s0A = 0.f, s0B = 0.f, s1A = 0.f, s1B = 0.f;
        #pragma unroll
        for (int reg = 0; reg < 16; ++reg) {
            const int rit = (reg & 3) + 8 * (reg >> 2) + 4 * khalf;
            const float v0 = leakyf(acc0[reg]);
            const float v1 = leakyf(acc1[reg]);
            if (rit >= bsplit) { s0B += v0; s1B += v1; }
            else               { s0A += v0; s1A += v1; }
        }
        s0A += __shfl_xor(s0A, 32); s0B += __shfl_xor(s0B, 32);
        s1A += __shfl_xor(s1A, 32); s1B += __shfl_xor(s1B, 32);
        const int q = ni & 1;
        if (khalf == 0) {
            Sw[q][wv][0][lrow]      = s0A;
            Sw[q][wv][0][32 + lrow] = s1A;
            if (bsplit < 32) {
                Sw[q][wv][1][lrow]      = s0B;
                Sw[q][wv][1][32 + lrow] = s1B;
            }
        }
        __syncthreads();   // Sw[q] complete; Bnxt staged

        if (tid < 128) {   // gather: img b = waves {b,slot1}+{b+1,slot0} (b>0)
            const int b = tid >> 4, j = tid & 15;
            const float4 ca4 = *reinterpret_cast<const float4*>(&cap_act [n * LATENT + g * CPG + j * 4]);
            const float4 cr4 = *reinterpret_cast<const float4*>(&cap_repr[n * LATENT + g * CPG + j * 4]);
            const float cav[4] = {ca4.x, ca4.y, ca4.z, ca4.w};
            const float crv[4] = {cr4.x, cr4.y, cr4.z, cr4.w};
            float d = 0.f, ss = 0.f;
            #pragma unroll
            for (int u = 0; u < 4; ++u) {
                const int o = j * 4 + u;
                const float S = (b == 0)
                    ? Sw[q][0][0][o] + Sw[q][1][0][o]
                    : Sw[q][b][1][o] + Sw[q][b + 1][0][o];
                const float tmp = S * cav[u];          // cap_act pre-scaled by 1/36
                d = fmaf(tmp, crv[u], d);
                ss = fmaf(tmp, tmp, ss);
            }
            #pragma unroll
            for (int off = 1; off <= 8; off <<= 1) {
                d += __shfl_xor(d, off);
                ss += __shfl_xor(ss, off);
            }
            if (j == 0) {
                part_dot[((size_t)n * BI + b0 + b) * NGROUPS + g] = d;
                part_ss [((size_t)n * BI + b0 + b) * NGROUPS + g] = ss;
            }
        }
    }
}

// ---------------------------------------------------------------------------
// Kernel 4: combine 16 group-partials -> sims[b*32+n]
// ---------------------------------------------------------------------------
__global__ __launch_bounds__(256) void final_kernel(
    const float* __restrict__ part_dot, const float* __restrict__ part_ss,
    const float* __restrict__ norm_capr, float* __restrict__ out)
{
    const int idx = blockIdx.x * 256 + threadIdx.x;   // 4096
    const int n = idx & 31;
    const int b = idx >> 5;
    const size_t base = ((size_t)n * BI + b) * NGROUPS;
    float d = 0.f, s = 0.f;
    #pragma unroll
    for (int g = 0; g < NGROUPS; ++g) { d += part_dot[base + g]; s += part_ss[base + g]; }
    out[b * BC + n] = d / (sqrtf(s) * norm_capr[n]);
}

// ---------------------------------------------------------------------------
extern "C" void kernel_launch(void* const* d_in, const int* in_sizes, int n_in,
                              void* d_out, int out_size, void* d_ws, size_t ws_size,
                              hipStream_t stream) {
    const float* img_embed = (const float*)d_in[0];   // (128, 36, 1024)
    const float* cap_embed = (const float*)d_in[1];   // (32, 50, 1024)
    const int*   lens      = (const int*)  d_in[2];   // (32,)
    const float* red_w     = (const float*)d_in[3];   // (1024, 256)
    const float* red_b     = (const float*)d_in[4];   // (256,)
    const float* proj_w    = (const float*)d_in[5];   // (256, 196608)
    const float* proj_b    = (const float*)d_in[6];   // (196608,)
    float* out = (float*)d_out;                        // (128, 32)

    char* ws = (char*)d_ws;
    unsigned short* Wp2F   = (unsigned short*)(ws);                    // 12,582,912 B
    float* cap_repr  = (float*)(ws + 22020096);                        //    131,072 B
    float* cap_act   = (float*)(ws + 22151168);                        //    131,072 B
    unsigned short* qbfF = (unsigned short*)(ws + 22282240);           //     16,384 B
    float* norm_capr = (float*)(ws + 22315008);                        //        512 B
    float* part_dot  = (float*)(ws + 22315520);                        //    262,144 B
    float* part_ss   = (float*)(ws + 22577664);                        //    262,144 B

    hipLaunchKernelGGL(cap_mean_kernel, dim3(BC), dim3(256), 0, stream,
                       cap_embed, lens, cap_repr, cap_act, norm_capr);
    hipLaunchKernelGGL(q_kernel, dim3(8, BC), dim3(256), 0, stream,
                       cap_repr, red_w, red_b, qbfF);
    hipLaunchKernelGGL(wgen13_kernel, dim3(256), dim3(768), 0, stream,
                       qbfF, proj_w, proj_b, Wp2F);
    hipLaunchKernelGGL(conv5_kernel, dim3(NGROUPS, 16, 2), dim3(576), 0, stream,
                       img_embed, Wp2F, cap_repr, cap_act, part_dot, part_ss);
    hipLaunchKernelGGL(final_kernel, dim3(16), dim3(256), 0, stream,
                       part_dot, part_ss, norm_capr, out);
}